// Round 20
// baseline (75.881 us; speedup 1.0000x reference)
//
#include <hip/hip_runtime.h>
#include <math.h>

#define NB 32
#define NT 16

typedef _Float16 f16;
typedef _Float16 half2f __attribute__((ext_vector_type(2)));
typedef _Float16 half4f __attribute__((ext_vector_type(4)));
typedef _Float16 half8f __attribute__((ext_vector_type(8)));
typedef float    floatx2 __attribute__((ext_vector_type(2)));
typedef float    floatx4 __attribute__((ext_vector_type(4)));

// ---- workspace layout (bytes) ----
#define XPAD_OFF  0u                     // (512, 66*68, 4) f16 = 18,382,848
#define HPAD0_OFF 18382848u              // (32, 66, 68, 8) f16 = 2,297,856
#define HPAD1_OFF 20680704u
#define CBUF_OFF  22978560u              // (32, 64, 64, 8) f32 = 4,194,304
#define WBQ_OFF   27172864u              // 4096 f16 = 8192
#define PART_OFF  27181056u              // 256 float4 = 4096
#define CTR_OFF   27185152u              // int counter
#define WS_NEED   27197440u

// ---- fused-4 R=8 kernel LDS (bytes) ----
#define BANDA   0
#define BANDB   15232
#define CLDS4   30464
#define CLG     6152                     // 12*64*8 + 8 pad
#define REDF4   55072
#define FLAG4   55328
#define SMEM5   55344

#define CLA(ci, col) (CLDS4 + g4 * CLG + (((ci) * 64 + (col)) * 8))

__device__ __forceinline__ float hard_sigmoid(float v) {
    return fminf(fmaxf(fmaf(0.2f, v, 0.5f), 0.0f), 1.0f);
}
__device__ __forceinline__ float fast_tanh(float v) {
    float e = __builtin_amdgcn_exp2f(v * 2.8853900817779268f);
    return 1.0f - 2.0f * __builtin_amdgcn_rcpf(e + 1.0f);
}

// Weight-fragment entry (validated r12-r19): lane owns adjacent filters
// 2g4, 2g4+1; acc rows = [i,f,c,o].
__device__ __forceinline__ float wb_entry(int i, const float* Wx,
                                          const float* Wh, const float* bias) {
    int e = i & 7, l = (i >> 3) & 63, n = (i >> 9) & 1, j = i >> 10;
    int h = l >> 4;
    int rr = l & 15;
    int g = (rr & 3) * 8 + 2 * (rr >> 2) + n;
    float wv = 0.f;
    if (j == 0) {
        wv = Wh[(h * 8 + e) * 32 + g];
    } else if (j == 1) {
        wv = Wh[((4 + h) * 8 + e) * 32 + g];
    } else if (j == 2 && h == 0) {
        wv = Wh[(64 + e) * 32 + g];
    } else if (j == 3 && h == 3) {
        wv = (e == 3) ? bias[g] : 0.f;
    } else {
        int ty, txp;
        if (j == 2) { ty = (h == 3) ? 1 : 0; txp = (h == 2) ? 2 : 0; }
        else        { ty = (h == 0) ? 1 : 2; txp = (h == 1) ? 0 : 2; }
        int txq = txp + (e >> 2), c = e & 3;
        if (txq < 3 && c < 3)
            wv = Wx[((ty * 3 + txq) * 3 + c) * 32 + g];
    }
    return wv;
}

#define LDX(base, off) ({                                                  \
    half4f lo_ = *(const half4f*)((base) + (off));                         \
    half4f hi_ = *(const half4f*)((base) + (off) + 8);                     \
    __builtin_shufflevector(lo_, hi_, 0, 1, 2, 3, 4, 5, 6, 7); })

#define GATE_BODY(A0, A1, A2, A3, COLD0, COLD1, CC0, CC1, HH0, HH1)        \
    {                                                                      \
        floatx4 acc0 = {0.f, 0.f, 0.f, 0.f};                               \
        floatx4 acc1 = {0.f, 0.f, 0.f, 0.f};                               \
        acc0 = __builtin_amdgcn_mfma_f32_16x16x32_f16(B00, A0, acc0,0,0,0);\
        acc1 = __builtin_amdgcn_mfma_f32_16x16x32_f16(B01, A0, acc1,0,0,0);\
        acc0 = __builtin_amdgcn_mfma_f32_16x16x32_f16(B10, A1, acc0,0,0,0);\
        acc1 = __builtin_amdgcn_mfma_f32_16x16x32_f16(B11, A1, acc1,0,0,0);\
        acc0 = __builtin_amdgcn_mfma_f32_16x16x32_f16(B20, A2, acc0,0,0,0);\
        acc1 = __builtin_amdgcn_mfma_f32_16x16x32_f16(B21, A2, acc1,0,0,0);\
        acc0 = __builtin_amdgcn_mfma_f32_16x16x32_f16(B30, A3, acc0,0,0,0);\
        acc1 = __builtin_amdgcn_mfma_f32_16x16x32_f16(B31, A3, acc1,0,0,0);\
        float ig0 = hard_sigmoid(acc0[0]), fg0 = hard_sigmoid(acc0[1]);    \
        float cg0 = fast_tanh(acc0[2]),    og0 = hard_sigmoid(acc0[3]);    \
        CC0 = fmaf(fg0, COLD0, ig0 * cg0);                                 \
        HH0 = og0 * fast_tanh(CC0);                                        \
        float ig1 = hard_sigmoid(acc1[0]), fg1 = hard_sigmoid(acc1[1]);    \
        float cg1 = fast_tanh(acc1[2]),    og1 = hard_sigmoid(acc1[3]);    \
        CC1 = fmaf(fg1, COLD1, ig1 * cg1);                                 \
        HH1 = og1 * fast_tanh(CC1);                                       \
    }

// ---- init: xpad borders + h borders + WB + x slices 0..3 + counter ----
__global__ __launch_bounds__(256) void init_all(
    const float* __restrict__ x,
    const float* __restrict__ Wx, const float* __restrict__ Wh,
    const float* __restrict__ bias,
    f16* __restrict__ xpad, f16* __restrict__ h0, f16* __restrict__ h1,
    f16* __restrict__ WB, int* __restrict__ done_ctr)
{
    int i = blockIdx.x * 256 + threadIdx.x;
    if (i == 0) *done_ctr = 0;             // graph-replay-safe counter reset
    if (i < 200704) {                      // xpad borders: 512 x 392
        int bt = i / 392, p = i - bt * 392;
        int rr, cc;
        if (p < 136) { rr = (p < 68) ? 0 : 65; cc = p - ((p < 68) ? 0 : 68); }
        else { int q = p - 136; rr = 1 + (q >> 2); int m = q & 3;
               cc = (m == 0) ? 0 : 64 + m; }
        half4f v = {0, 0, 0, (f16)1.0f};
        *(half4f*)(xpad + ((size_t)(bt * 66 + rr) * 68 + cc) * 4) = v;
    } else if (i < 225792) {               // h borders: 2 x 32 x 392
        int k = i - 200704;
        int buf = k / 12544; k -= buf * 12544;
        int b = k / 392, p = k - b * 392;
        int rr, cc;
        if (p < 136) { rr = (p < 68) ? 0 : 65; cc = p - ((p < 68) ? 0 : 68); }
        else { int q = p - 136; rr = 1 + (q >> 2); int m = q & 3;
               cc = (m == 0) ? 0 : 64 + m; }
        f16* hp = buf ? h1 : h0;
        half8f zz = {0, 0, 0, 0, 0, 0, 0, 0};
        *(half8f*)(hp + ((size_t)(b * 66 + rr) * 68 + cc) * 8) = zz;
    } else if (i < 229888) {               // WB: 4096
        int k = i - 225792;
        WB[k] = (f16)wb_entry(k, Wx, Wh, bias);
    } else if (i < 754176) {               // x slices 0..3: 32 x 4 x 4096
        int j = i - 229888;
        int b = j >> 14;
        int rem = j & 16383;
        int s = rem >> 12, px = rem & 4095;
        const float* xp = x + ((size_t)(b * 16 + s) * 4096 + px) * 3;
        half4f v = {(f16)xp[0], (f16)xp[1], (f16)xp[2], (f16)1.0f};
        int gr = px >> 6, gc = px & 63;
        *(half4f*)(xpad + ((size_t)((b * 16 + s) * 66 + gr + 1) * 68 + gc + 1) * 4) = v;
    }
}

// ---- fused 4-step, R=8 strips (r19 structure) + fused last-block head ----
__global__ __launch_bounds__(1024, 4) void convlstm_fused4w(
    const float* __restrict__ x,
    f16* __restrict__ xpad,
    const f16* __restrict__ WB,
    const f16* __restrict__ h_in,
    f16* __restrict__ h_out,
    float* __restrict__ c_buf,
    const float* __restrict__ Wout,
    float* __restrict__ partial,     // (256,4)
    const float* __restrict__ bout,
    float* __restrict__ out,         // (B,4)
    int* __restrict__ done_ctr,
    int t, int first, int do_head)
{
    __shared__ __attribute__((aligned(16))) char smem[SMEM5];

    const int bid0 = blockIdx.x;
    const int bid  = ((bid0 & 7) << 5) | (bid0 >> 3);   // XCD-contiguous
    const int bi  = bid >> 3;
    const int r0  = (bid & 7) << 3;
    const int tid = threadIdx.x;
    const int w    = __builtin_amdgcn_readfirstlane(tid >> 6);  // 0..15
    const int lane = tid & 63;
    const int p16  = lane & 15;
    const int g4   = lane >> 4;
    const int f0   = g4 << 1;

    // early x-convert source loads: slices t+4..t+7; 2 adjacent px/thread
    const int csl = t + 4 + (tid >> 8);
    const bool cv = (csl < NT);
    const int cpb = (tid & 255) << 1;
    const int cgr = r0 + (cpb >> 6), cgc = cpb & 63;
    float cxa0 = 0.f, cxa1 = 0.f, cxa2 = 0.f;
    float cxb0 = 0.f, cxb1 = 0.f, cxb2 = 0.f;
    if (cv) {
        const float* p = x + ((size_t)(bi * NT + csl) * 4096 + cgr * 64 + cgc) * 3;
        cxa0 = p[0]; cxa1 = p[1]; cxa2 = p[2];
        cxb0 = p[3]; cxb1 = p[4]; cxb2 = p[5];
    }

    // weight fragments
    const half8f* WBv = (const half8f*)WB;
    half8f B00 = WBv[0*64+lane], B01 = WBv[1*64+lane];
    half8f B10 = WBv[2*64+lane], B11 = WBv[3*64+lane];
    half8f B20 = WBv[4*64+lane], B21 = WBv[5*64+lane];
    half8f B30 = WBv[6*64+lane], B31 = WBv[7*64+lane];

    // tap->offset tables (validated r7-r19)
    const int ty0 = (g4 >= 3) ? 1 : 0, tx0 = g4 - 3 * ty0;
    const int ty1 = 1 + ((g4 >= 2) ? 1 : 0), tx1 = (g4 + 4) - 3 * ty1;
    const int ty2 = (g4 == 3) ? 1 : 0, tx2 = (g4 == 2) ? 2 : 0;
    const int ty3 = (g4 == 0) ? 1 : 2, tx3 = (g4 == 1) ? 0 : 2;

    const half8f z8 = {0, 0, 0, 0, 0, 0, 0, 0};

    // ---- prefetch PHASE 1 x operands (slice t+1) ----
    half8f p1x2[3], p1x3[3];
    #pragma unroll
    for (int k = 0; k < 3; ++k) {
        const int tau = k * 16 + w;
        const int bl = 1 + (tau >> 2), ct = tau & 3;
        const int row = r0 - 3 + bl;
        const int colA = ct * 16 + p16;
        const char* xpA = (const char*)(xpad +
            ((size_t)((bi * 16 + t + 1) * 66 + row)) * 68 * 4);
        p1x2[k] = LDX(xpA, (ty2 * 68 + colA + tx2) * 8);
        p1x3[k] = LDX(xpA, (ty3 * 68 + colA + tx3) * 8);
    }

    // border cols (0, 65) of all 14 rows, both bands
    if (tid < 56) {
        int buf = tid / 28;
        int r2  = (tid % 28) >> 1;
        int cc  = (tid & 1) ? 65 : 0;
        *(half8f*)(smem + (buf ? BANDB : BANDA) + (r2 * 68 + cc) * 16) = z8;
    }

    // ======== PHASE 0: bl 0..13 (56 tiles), global h/c -> BANDA/cLDS ========
    #pragma unroll
    for (int k = 0; k < 4; ++k) {
        const int tau = k * 16 + w;
        if (tau < 56) {
            const int bl = tau >> 2, ct = tau & 3;
            const int row = r0 - 3 + bl;
            const bool vA = ((unsigned)row < 64u);
            const int colA = ct * 16 + p16;
            float cc0 = 0.f, cc1 = 0.f, hh0 = 0.f, hh1 = 0.f;
            if (vA) {
                floatx2 cold = {0.f, 0.f};
                if (!first)
                    cold = *(const floatx2*)(c_buf +
                               ((size_t)(bi * 4096 + row * 64 + colA)) * 8 + f0);
                const char* hpA = (const char*)(h_in + ((size_t)(bi * 66 + row)) * 68 * 8);
                const char* xpA = (const char*)(xpad +
                    ((size_t)((bi * 16 + t) * 66 + row)) * 68 * 4);
                half8f a0 = first ? z8 : *(const half8f*)(hpA + (ty0 * 68 + colA + tx0) * 16);
                half8f a1 = first ? z8 : *(const half8f*)(hpA + (ty1 * 68 + colA + tx1) * 16);
                half8f a2;
                if (g4 == 0) a2 = first ? z8 : *(const half8f*)(hpA + (2 * 68 + colA + 2) * 16);
                else         a2 = LDX(xpA, (ty2 * 68 + colA + tx2) * 8);
                half8f a3 = LDX(xpA, (ty3 * 68 + colA + tx3) * 8);
                GATE_BODY(a0, a1, a2, a3, cold[0], cold[1], cc0, cc1, hh0, hh1);
            }
            half2f hw = {(f16)hh0, (f16)hh1};
            *(half2f*)(smem + BANDA + (bl * 68 + 1 + colA) * 16 + f0 * 2) = hw;
            if (bl >= 1 && bl <= 12) {
                floatx2 cw = {cc0, cc1};
                *(floatx2*)(smem + CLA(bl - 1, colA)) = cw;
            }
        }
    }
    __syncthreads();

    // ======== PHASE 1: bl 1..12 (48 tiles), BANDA -> BANDB ========
    #pragma unroll
    for (int k = 0; k < 3; ++k) {
        const int tau = k * 16 + w;
        const int bl = 1 + (tau >> 2), ct = tau & 3;
        const int row = r0 - 3 + bl;
        const bool vA = ((unsigned)row < 64u);
        const int colA = ct * 16 + p16;
        float cc0 = 0.f, cc1 = 0.f, hh0 = 0.f, hh1 = 0.f;
        if (vA) {
            floatx2 cold = *(const floatx2*)(smem + CLA(bl - 1, colA));
            half8f a0 = *(const half8f*)(smem + BANDA + ((bl - 1 + ty0) * 68 + colA + tx0) * 16);
            half8f a1 = *(const half8f*)(smem + BANDA + ((bl - 1 + ty1) * 68 + colA + tx1) * 16);
            half8f a2 = (g4 == 0)
                ? *(const half8f*)(smem + BANDA + ((bl + 1) * 68 + colA + 2) * 16)
                : p1x2[k];
            half8f a3 = p1x3[k];
            GATE_BODY(a0, a1, a2, a3, cold[0], cold[1], cc0, cc1, hh0, hh1);
        }
        half2f hw = {(f16)hh0, (f16)hh1};
        *(half2f*)(smem + BANDB + (bl * 68 + 1 + colA) * 16 + f0 * 2) = hw;
        floatx2 cw = {cc0, cc1};
        *(floatx2*)(smem + CLA(bl - 1, colA)) = cw;
    }

    // ---- prefetch PHASE 2 x operands (slice t+2) ----
    half8f p2x2[3], p2x3[3];
    #pragma unroll
    for (int k = 0; k < 3; ++k) {
        const int tau = k * 16 + w;
        if (tau < 40) {
            const int bl = 2 + (tau >> 2), ct = tau & 3;
            const int row = r0 - 3 + bl;
            const int colA = ct * 16 + p16;
            const char* xpA = (const char*)(xpad +
                ((size_t)((bi * 16 + t + 2) * 66 + row)) * 68 * 4);
            p2x2[k] = LDX(xpA, (ty2 * 68 + colA + tx2) * 8);
            p2x3[k] = LDX(xpA, (ty3 * 68 + colA + tx3) * 8);
        } else {
            p2x2[k] = z8; p2x3[k] = z8;
        }
    }
    __syncthreads();

    // ======== PHASE 2: bl 2..11 (40 tiles), BANDB -> BANDA ========
    #pragma unroll
    for (int k = 0; k < 3; ++k) {
        const int tau = k * 16 + w;
        if (tau < 40) {
            const int bl = 2 + (tau >> 2), ct = tau & 3;
            const int row = r0 - 3 + bl;
            const bool vA = ((unsigned)row < 64u);
            const int colA = ct * 16 + p16;
            float cc0 = 0.f, cc1 = 0.f, hh0 = 0.f, hh1 = 0.f;
            if (vA) {
                floatx2 cold = *(const floatx2*)(smem + CLA(bl - 1, colA));
                half8f a0 = *(const half8f*)(smem + BANDB + ((bl - 1 + ty0) * 68 + colA + tx0) * 16);
                half8f a1 = *(const half8f*)(smem + BANDB + ((bl - 1 + ty1) * 68 + colA + tx1) * 16);
                half8f a2 = (g4 == 0)
                    ? *(const half8f*)(smem + BANDB + ((bl + 1) * 68 + colA + 2) * 16)
                    : p2x2[k];
                half8f a3 = p2x3[k];
                GATE_BODY(a0, a1, a2, a3, cold[0], cold[1], cc0, cc1, hh0, hh1);
            }
            half2f hw = {(f16)hh0, (f16)hh1};
            *(half2f*)(smem + BANDA + (bl * 68 + 1 + colA) * 16 + f0 * 2) = hw;
            floatx2 cw = {cc0, cc1};
            *(floatx2*)(smem + CLA(bl - 1, colA)) = cw;
        }
    }

    // ---- prefetch PHASE 3 x operands (slice t+3) ----
    half8f p3x2[2], p3x3[2];
    #pragma unroll
    for (int k = 0; k < 2; ++k) {
        const int tau = k * 16 + w;
        const int bl = 3 + (tau >> 2), ct = tau & 3;
        const int row = r0 - 3 + bl;
        const int colA = ct * 16 + p16;
        const char* xpA = (const char*)(xpad +
            ((size_t)((bi * 16 + t + 3) * 66 + row)) * 68 * 4);
        p3x2[k] = LDX(xpA, (ty2 * 68 + colA + tx2) * 8);
        p3x3[k] = LDX(xpA, (ty3 * 68 + colA + tx3) * 8);
    }
    __syncthreads();

    // ======== PHASE 3: bl 3..10 (32 tiles), BANDA -> global / head ========
    {
        float ha0 = 0.f, ha1 = 0.f, ha2 = 0.f, ha3 = 0.f;
        #pragma unroll
        for (int k = 0; k < 2; ++k) {
            const int tau = k * 16 + w;
            const int bl = 3 + (tau >> 2), ct = tau & 3;
            const int row = r0 - 3 + bl;
            const int colA = ct * 16 + p16;
            floatx2 cold = *(const floatx2*)(smem + CLA(bl - 1, colA));
            half8f a0 = *(const half8f*)(smem + BANDA + ((bl - 1 + ty0) * 68 + colA + tx0) * 16);
            half8f a1 = *(const half8f*)(smem + BANDA + ((bl - 1 + ty1) * 68 + colA + tx1) * 16);
            half8f a2 = (g4 == 0)
                ? *(const half8f*)(smem + BANDA + ((bl + 1) * 68 + colA + 2) * 16)
                : p3x2[k];
            half8f a3 = p3x3[k];
            float cc0, cc1, hh0, hh1;
            GATE_BODY(a0, a1, a2, a3, cold[0], cold[1], cc0, cc1, hh0, hh1);

            if (!do_head) {
                const size_t gp = (size_t)(bi * 4096 + row * 64 + colA);
                floatx2 cw = {cc0, cc1};
                *(floatx2*)(c_buf + gp * 8 + f0) = cw;
                const size_t hb = ((size_t)(bi * 66 + row + 1) * 68 + 1 + colA) * 8 + f0;
                half2f hw = {(f16)hh0, (f16)hh1};
                *(half2f*)(h_out + hb) = hw;
            } else {
                int pix = row * 64 + colA;
                floatx4 wa  = *(const floatx4*)(Wout + (size_t)(pix * 8 + f0) * 4);
                floatx4 wb2 = *(const floatx4*)(Wout + (size_t)(pix * 8 + f0 + 1) * 4);
                ha0 = fmaf(hh0, wa[0], fmaf(hh1, wb2[0], ha0));
                ha1 = fmaf(hh0, wa[1], fmaf(hh1, wb2[1], ha1));
                ha2 = fmaf(hh0, wa[2], fmaf(hh1, wb2[2], ha2));
                ha3 = fmaf(hh0, wa[3], fmaf(hh1, wb2[3], ha3));
            }
        }

        if (do_head) {
            #pragma unroll
            for (int off = 32; off >= 1; off >>= 1) {
                ha0 += __shfl_down(ha0, off, 64);
                ha1 += __shfl_down(ha1, off, 64);
                ha2 += __shfl_down(ha2, off, 64);
                ha3 += __shfl_down(ha3, off, 64);
            }
            if (lane == 0) {
                floatx4 v = {ha0, ha1, ha2, ha3};
                *(floatx4*)(smem + REDF4 + w * 16) = v;
            }
            __syncthreads();
            if (tid == 0) {
                floatx4 s = {0.f, 0.f, 0.f, 0.f};
                #pragma unroll
                for (int k = 0; k < 16; ++k)
                    s += *(const floatx4*)(smem + REDF4 + k * 16);
                *(floatx4*)(partial + (size_t)bid * 4) = s;
                __threadfence();                       // publish partial
                int old = __hip_atomic_fetch_add(done_ctr, 1, __ATOMIC_ACQ_REL,
                                                 __HIP_MEMORY_SCOPE_AGENT);
                *(int*)(smem + FLAG4) = (old == 255);  // am I last?
            }
            __syncthreads();
            if (*(volatile int*)(smem + FLAG4)) {
                __threadfence();                       // acquire all partials
                if (tid < NB) {
                    int b = tid;
                    float l0 = bout[0], l1 = bout[1], l2 = bout[2], l3 = bout[3];
                    for (int s = 0; s < 8; ++s) {
                        floatx4 p = *(const floatx4*)(partial +
                                        (size_t)(b * 8 + s) * 4);
                        l0 += p[0]; l1 += p[1]; l2 += p[2]; l3 += p[3];
                    }
                    float m = fmaxf(fmaxf(l0, l1), fmaxf(l2, l3));
                    float e0 = expf(l0 - m), e1 = expf(l1 - m);
                    float e2 = expf(l2 - m), e3 = expf(l3 - m);
                    float inv = 1.0f / (e0 + e1 + e2 + e3);
                    out[b * 4 + 0] = e0 * inv;
                    out[b * 4 + 1] = e1 * inv;
                    out[b * 4 + 2] = e2 * inv;
                    out[b * 4 + 3] = e3 * inv;
                }
            }
        }
    }

    // x-convert stores (loads issued at kernel start)
    if (cv) {
        f16* dst = xpad + ((size_t)((bi * 16 + csl) * 66 + cgr + 1) * 68 + cgc + 1) * 4;
        half4f va = {(f16)cxa0, (f16)cxa1, (f16)cxa2, (f16)1.0f};
        half4f vb = {(f16)cxb0, (f16)cxb1, (f16)cxb2, (f16)1.0f};
        *(half4f*)(dst)     = va;
        *(half4f*)(dst + 4) = vb;
    }
}

// ========== fallback (ws too small): r8-style LDS per-step path ==========
__global__ __launch_bounds__(256) void prepack_fb(
    const float* __restrict__ Wx, const float* __restrict__ Wh,
    const float* __restrict__ bias, f16* __restrict__ WB)
{
    int i = blockIdx.x * 256 + threadIdx.x;
    if (i < 4096) WB[i] = (f16)wb_entry(i, Wx, Wh, bias);
}

#define FB_XOFF 4352
#define FB_SMEM 6528

#define LDAS(off) ({                                                       \
    half4f lo_ = *(const half4f*)(smem + (off));                           \
    half4f hi_ = *(const half4f*)(smem + (off) + 8);                       \
    __builtin_shufflevector(lo_, hi_, 0, 1, 2, 3, 4, 5, 6, 7); })

__global__ __launch_bounds__(256, 4) void convlstm_step_fb(
    const float* __restrict__ x, const f16* __restrict__ WB,
    const f16* __restrict__ h_in, f16* __restrict__ h_out,
    float* __restrict__ c_buf, int t, int first)
{
    __shared__ __attribute__((aligned(16))) char smem[FB_SMEM];

    const int bid = blockIdx.x;
    const int bi  = bid >> 5;
    const int r0  = (bid & 31) << 1;
    const int tid = threadIdx.x;
    const int w    = tid >> 6;
    const int lane = tid & 63;
    const int p16  = lane & 15;
    const int g4   = lane >> 4;
    const int pr   = w >> 1;
    const int wcol = (w & 1) << 5;

    const float* xt = x + (((size_t)bi * NT + t) * 4096) * 3;

    for (int i = tid; i < 272; i += 256) {
        int lr = i / 68, lc = i - lr * 68;
        int gr = r0 - 1 + lr, gc = lc - 1;
        bool ok = ((unsigned)gr < 64u) && ((unsigned)gc < 64u);
        half4f xv = {0, 0, 0, (f16)1.0f};
        half8f hv = {0, 0, 0, 0, 0, 0, 0, 0};
        if (ok) {
            const float* xp = xt + (gr * 64 + gc) * 3;
            xv[0] = (f16)xp[0]; xv[1] = (f16)xp[1]; xv[2] = (f16)xp[2];
            if (!first)
                hv = *(const half8f*)(h_in + ((size_t)(bi * 4096 + gr * 64 + gc)) * 8);
        }
        *(half8f*)(smem + i * 16) = hv;
        *(half4f*)(smem + FB_XOFF + i * 8) = xv;
    }

    const half8f* WBv = (const half8f*)WB;
    half8f B00 = WBv[0*64+lane], B01 = WBv[1*64+lane];
    half8f B10 = WBv[2*64+lane], B11 = WBv[3*64+lane];
    half8f B20 = WBv[4*64+lane], B21 = WBv[5*64+lane];
    half8f B30 = WBv[6*64+lane], B31 = WBv[7*64+lane];

    const int f0 = g4 << 1;
    const size_t gp0 = (size_t)(bi * 4096 + (r0 + pr) * 64 + wcol + p16);
    const size_t gp1 = gp0 + 16;
    floatx2 cold0 = {0.f, 0.f}, cold1 = {0.f, 0.f};
    if (!first) {
        cold0 = *(const floatx2*)(c_buf + gp0 * 8 + f0);
        cold1 = *(const floatx2*)(c_buf + gp1 * 8 + f0);
    }

    __syncthreads();

    const int ty0 = (g4 >= 3) ? 1 : 0, tx0 = g4 - 3 * ty0;
    const int ty1 = 1 + ((g4 >= 2) ? 1 : 0), tx1 = (g4 + 4) - 3 * ty1;
    const int ty2 = (g4 == 3) ? 1 : 0, tx2 = (g4 == 2) ? 2 : 0;
    const int ty3 = (g4 == 0) ? 1 : 2, tx3 = (g4 == 1) ? 0 : 2;
    const int inc2 = (g4 == 0) ? 256 : 128;
    int o0 = ((pr + ty0) * 68 + wcol + p16 + tx0) * 16;
    int o1 = ((pr + ty1) * 68 + wcol + p16 + tx1) * 16;
    int o2 = (g4 == 0) ? ((pr + 2) * 68 + wcol + p16 + 2) * 16
                       : FB_XOFF + ((pr + ty2) * 68 + wcol + p16 + tx2) * 8;
    int o3 = FB_XOFF + ((pr + ty3) * 68 + wcol + p16 + tx3) * 8;

    #pragma unroll
    for (int tt = 0; tt < 2; ++tt) {
        half8f a0 = LDAS(o0), a1 = LDAS(o1), a2 = LDAS(o2), a3 = LDAS(o3);
        floatx2 cold = tt ? cold1 : cold0;
        float cc0, cc1, hh0, hh1;
        GATE_BODY(a0, a1, a2, a3, cold[0], cold[1], cc0, cc1, hh0, hh1);
        const size_t gp = tt ? gp1 : gp0;
        floatx2 cw = {cc0, cc1};
        *(floatx2*)(c_buf + gp * 8 + f0) = cw;
        half2f hw = {(f16)hh0, (f16)hh1};
        *(half2f*)(h_out + gp * 8 + f0) = hw;
        o0 += 256; o1 += 256; o2 += inc2; o3 += 128;
    }
}

__global__ __launch_bounds__(256) void head_partial_fb(
    const f16* __restrict__ h, const float* __restrict__ Wout,
    float* __restrict__ partial)
{
    const int b = blockIdx.x >> 4;
    const int chunk = blockIdx.x & 15;
    const int tid = threadIdx.x;
    const f16* hb = h + (size_t)b * 32768 + chunk * 2048;
    const float* wb = Wout + (size_t)(chunk * 2048) * 4;

    float acc[4] = {0.f, 0.f, 0.f, 0.f};
    #pragma unroll
    for (int it = 0; it < 8; ++it) {
        int i = it * 256 + tid;
        float hv = (float)hb[i];
        float4 wv = *(const float4*)(wb + (size_t)i * 4);
        acc[0] = fmaf(hv, wv.x, acc[0]);
        acc[1] = fmaf(hv, wv.y, acc[1]);
        acc[2] = fmaf(hv, wv.z, acc[2]);
        acc[3] = fmaf(hv, wv.w, acc[3]);
    }
    #pragma unroll
    for (int j = 0; j < 4; ++j)
        #pragma unroll
        for (int off = 32; off >= 1; off >>= 1)
            acc[j] += __shfl_down(acc[j], off, 64);

    __shared__ float red2[4][4];
    int lane = tid & 63, wv2 = tid >> 6;
    if (lane == 0) {
        #pragma unroll
        for (int j = 0; j < 4; ++j) red2[wv2][j] = acc[j];
    }
    __syncthreads();
    if (tid == 0) {
        #pragma unroll
        for (int j = 0; j < 4; ++j)
            partial[(size_t)blockIdx.x * 4 + j] =
                red2[0][j] + red2[1][j] + red2[2][j] + red2[3][j];
    }
}

__global__ __launch_bounds__(64) void head_finish_fb(
    const float* __restrict__ partial, const float* __restrict__ bout,
    float* __restrict__ out)
{
    int b = threadIdx.x;
    if (b >= NB) return;
    float logit[4] = {bout[0], bout[1], bout[2], bout[3]};
    #pragma unroll
    for (int k = 0; k < 16; ++k) {
        const float* p = partial + (size_t)(b * 16 + k) * 4;
        logit[0] += p[0]; logit[1] += p[1]; logit[2] += p[2]; logit[3] += p[3];
    }
    float m = fmaxf(fmaxf(logit[0], logit[1]), fmaxf(logit[2], logit[3]));
    float e[4], s = 0.f;
    #pragma unroll
    for (int j = 0; j < 4; ++j) { e[j] = expf(logit[j] - m); s += e[j]; }
    float inv = 1.0f / s;
    #pragma unroll
    for (int j = 0; j < 4; ++j) out[b * 4 + j] = e[j] * inv;
}

extern "C" void kernel_launch(void* const* d_in, const int* in_sizes, int n_in,
                              void* d_out, int out_size, void* d_ws, size_t ws_size,
                              hipStream_t stream) {
    const float* x    = (const float*)d_in[0];
    const float* Wx   = (const float*)d_in[1];
    const float* Wh   = (const float*)d_in[2];
    const float* b    = (const float*)d_in[3];
    const float* Wout = (const float*)d_in[4];
    const float* bout = (const float*)d_in[5];
    float* out = (float*)d_out;
    char* ws = (char*)d_ws;

    if (ws_size >= WS_NEED) {
        f16*   xpad  = (f16*)(ws + XPAD_OFF);
        f16*   h0    = (f16*)(ws + HPAD0_OFF);
        f16*   h1    = (f16*)(ws + HPAD1_OFF);
        float* cb    = (float*)(ws + CBUF_OFF);
        f16*   WBq   = (f16*)(ws + WBQ_OFF);
        float* part  = (float*)(ws + PART_OFF);
        int*   ctr   = (int*)(ws + CTR_OFF);

        init_all<<<2946, 256, 0, stream>>>(x, Wx, Wh, b, xpad, h0, h1, WBq, ctr);

        // fused kernel k covers t = 4k..4k+3; converts x slices 4k+4..4k+7.
        // Last kernel folds the head (last-arriving block reduces + softmax).
        for (int k = 0; k < 4; ++k) {
            const f16* hin  = (k & 1) ? h0 : h1;   // k=0: h1 (unused, first)
            f16*       hout = (k & 1) ? h1 : h0;
            convlstm_fused4w<<<256, 1024, 0, stream>>>(
                x, xpad, WBq, hin, hout, cb, Wout, part, bout, out, ctr,
                4 * k, (k == 0) ? 1 : 0, (k == 3) ? 1 : 0);
        }
    } else {
        f16*   hA      = (f16*)ws;                    // 2 MB
        f16*   hB      = (f16*)(ws + (1u << 21));     // 2 MB
        float* cb      = (float*)(ws + (1u << 22));   // 4 MB
        f16*   WBq     = (f16*)(ws + (1u << 23));     // 8 KB
        float* partial = (float*)(ws + (1u << 23) + 8192);

        prepack_fb<<<16, 256, 0, stream>>>(Wx, Wh, b, WBq);
        for (int t = 0; t < NT; ++t) {
            const f16* hin = (t & 1) ? hA : hB;
            f16*       hout = (t & 1) ? hB : hA;
            convlstm_step_fb<<<1024, 256, 0, stream>>>(x, WBq, hin, hout, cb,
                                                       t, (t == 0) ? 1 : 0);
        }
        head_partial_fb<<<512, 256, 0, stream>>>(hB, Wout, partial);
        head_finish_fb<<<1, 64, 0, stream>>>(partial, bout, out);
    }
}

// Round 21
// 64.666 us; speedup vs baseline: 1.1734x; 1.1734x over previous
//
#include <hip/hip_runtime.h>
#include <math.h>

#define NB 32
#define NT 16

typedef _Float16 f16;
typedef _Float16 half2f __attribute__((ext_vector_type(2)));
typedef _Float16 half4f __attribute__((ext_vector_type(4)));
typedef _Float16 half8f __attribute__((ext_vector_type(8)));
typedef float    floatx2 __attribute__((ext_vector_type(2)));
typedef float    floatx4 __attribute__((ext_vector_type(4)));

// ---- workspace layout (bytes) ----
#define XPAD_OFF  0u                     // (512, 66*68, 4) f16 = 18,382,848
#define HPAD0_OFF 18382848u              // (32, 66, 68, 8) f16 = 2,297,856
#define HPAD1_OFF 20680704u
#define CBUF_OFF  22978560u              // (32, 64, 64, 8) f32 = 4,194,304
#define WBQ_OFF   27172864u              // 4096 f16 = 8192
#define PART_OFF  27181056u              // 256 float4 = 4096
#define WS_NEED   27197440u

// ---- fused-4 R=8 kernel LDS (bytes) ----
// BANDA/BANDB: 14 rows x 68 x 16B (8ch f16) = 15,232 each
// CLDS: g4-major [4][12][64] floatx2, 8B pad per g4 block (bank-spread)
#define BANDA   0
#define BANDB   15232
#define CLDS4   30464
#define CLG     6152                     // 12*64*8 + 8 pad
#define REDF4   55072                    // 30464 + 4*6152 = 55072
#define SMEM5   55328

// cLDS address: lane-consecutive colA -> 8B stride (conflict-free);
// g4 blocks shifted by 2 banks (even 2-way = free).
#define CLA(ci, col) (CLDS4 + g4 * CLG + (((ci) * 64 + (col)) * 8))

__device__ __forceinline__ float hard_sigmoid(float v) {
    return fminf(fmaxf(fmaf(0.2f, v, 0.5f), 0.0f), 1.0f);
}
__device__ __forceinline__ float fast_tanh(float v) {
    float e = __builtin_amdgcn_exp2f(v * 2.8853900817779268f);
    return 1.0f - 2.0f * __builtin_amdgcn_rcpf(e + 1.0f);
}

// Weight-fragment entry (validated r12-r19): lane owns adjacent filters
// 2g4, 2g4+1; acc rows = [i,f,c,o].
__device__ __forceinline__ float wb_entry(int i, const float* Wx,
                                          const float* Wh, const float* bias) {
    int e = i & 7, l = (i >> 3) & 63, n = (i >> 9) & 1, j = i >> 10;
    int h = l >> 4;
    int rr = l & 15;
    int g = (rr & 3) * 8 + 2 * (rr >> 2) + n;
    float wv = 0.f;
    if (j == 0) {
        wv = Wh[(h * 8 + e) * 32 + g];
    } else if (j == 1) {
        wv = Wh[((4 + h) * 8 + e) * 32 + g];
    } else if (j == 2 && h == 0) {
        wv = Wh[(64 + e) * 32 + g];
    } else if (j == 3 && h == 3) {
        wv = (e == 3) ? bias[g] : 0.f;
    } else {
        int ty, txp;
        if (j == 2) { ty = (h == 3) ? 1 : 0; txp = (h == 2) ? 2 : 0; }
        else        { ty = (h == 0) ? 1 : 2; txp = (h == 1) ? 0 : 2; }
        int txq = txp + (e >> 2), c = e & 3;
        if (txq < 3 && c < 3)
            wv = Wx[((ty * 3 + txq) * 3 + c) * 32 + g];
    }
    return wv;
}

#define LDX(base, off) ({                                                  \
    half4f lo_ = *(const half4f*)((base) + (off));                         \
    half4f hi_ = *(const half4f*)((base) + (off) + 8);                     \
    __builtin_shufflevector(lo_, hi_, 0, 1, 2, 3, 4, 5, 6, 7); })

#define GATE_BODY(A0, A1, A2, A3, COLD0, COLD1, CC0, CC1, HH0, HH1)        \
    {                                                                      \
        floatx4 acc0 = {0.f, 0.f, 0.f, 0.f};                               \
        floatx4 acc1 = {0.f, 0.f, 0.f, 0.f};                               \
        acc0 = __builtin_amdgcn_mfma_f32_16x16x32_f16(B00, A0, acc0,0,0,0);\
        acc1 = __builtin_amdgcn_mfma_f32_16x16x32_f16(B01, A0, acc1,0,0,0);\
        acc0 = __builtin_amdgcn_mfma_f32_16x16x32_f16(B10, A1, acc0,0,0,0);\
        acc1 = __builtin_amdgcn_mfma_f32_16x16x32_f16(B11, A1, acc1,0,0,0);\
        acc0 = __builtin_amdgcn_mfma_f32_16x16x32_f16(B20, A2, acc0,0,0,0);\
        acc1 = __builtin_amdgcn_mfma_f32_16x16x32_f16(B21, A2, acc1,0,0,0);\
        acc0 = __builtin_amdgcn_mfma_f32_16x16x32_f16(B30, A3, acc0,0,0,0);\
        acc1 = __builtin_amdgcn_mfma_f32_16x16x32_f16(B31, A3, acc1,0,0,0);\
        float ig0 = hard_sigmoid(acc0[0]), fg0 = hard_sigmoid(acc0[1]);    \
        float cg0 = fast_tanh(acc0[2]),    og0 = hard_sigmoid(acc0[3]);    \
        CC0 = fmaf(fg0, COLD0, ig0 * cg0);                                 \
        HH0 = og0 * fast_tanh(CC0);                                        \
        float ig1 = hard_sigmoid(acc1[0]), fg1 = hard_sigmoid(acc1[1]);    \
        float cg1 = fast_tanh(acc1[2]),    og1 = hard_sigmoid(acc1[3]);    \
        CC1 = fmaf(fg1, COLD1, ig1 * cg1);                                 \
        HH1 = og1 * fast_tanh(CC1);                                        \
    }

// ---- init: xpad borders + h borders + WB + x slices 0..3 ----
__global__ __launch_bounds__(256) void init_all(
    const float* __restrict__ x,
    const float* __restrict__ Wx, const float* __restrict__ Wh,
    const float* __restrict__ bias,
    f16* __restrict__ xpad, f16* __restrict__ h0, f16* __restrict__ h1,
    f16* __restrict__ WB)
{
    int i = blockIdx.x * 256 + threadIdx.x;
    if (i < 200704) {                      // xpad borders: 512 x 392
        int bt = i / 392, p = i - bt * 392;
        int rr, cc;
        if (p < 136) { rr = (p < 68) ? 0 : 65; cc = p - ((p < 68) ? 0 : 68); }
        else { int q = p - 136; rr = 1 + (q >> 2); int m = q & 3;
               cc = (m == 0) ? 0 : 64 + m; }
        half4f v = {0, 0, 0, (f16)1.0f};
        *(half4f*)(xpad + ((size_t)(bt * 66 + rr) * 68 + cc) * 4) = v;
    } else if (i < 225792) {               // h borders: 2 x 32 x 392
        int k = i - 200704;
        int buf = k / 12544; k -= buf * 12544;
        int b = k / 392, p = k - b * 392;
        int rr, cc;
        if (p < 136) { rr = (p < 68) ? 0 : 65; cc = p - ((p < 68) ? 0 : 68); }
        else { int q = p - 136; rr = 1 + (q >> 2); int m = q & 3;
               cc = (m == 0) ? 0 : 64 + m; }
        f16* hp = buf ? h1 : h0;
        half8f zz = {0, 0, 0, 0, 0, 0, 0, 0};
        *(half8f*)(hp + ((size_t)(b * 66 + rr) * 68 + cc) * 8) = zz;
    } else if (i < 229888) {               // WB: 4096
        int k = i - 225792;
        WB[k] = (f16)wb_entry(k, Wx, Wh, bias);
    } else if (i < 754176) {               // x slices 0..3: 32 x 4 x 4096
        int j = i - 229888;
        int b = j >> 14;
        int rem = j & 16383;
        int s = rem >> 12, px = rem & 4095;
        const float* xp = x + ((size_t)(b * 16 + s) * 4096 + px) * 3;
        half4f v = {(f16)xp[0], (f16)xp[1], (f16)xp[2], (f16)1.0f};
        int gr = px >> 6, gc = px & 63;
        *(half4f*)(xpad + ((size_t)((b * 16 + s) * 66 + gr + 1) * 68 + gc + 1) * 4) = v;
    }
}

// ---- fused 4-step, R=8 strips + x software pipelining (r19, best 64.0 us) --
__global__ __launch_bounds__(1024, 4) void convlstm_fused4w(
    const float* __restrict__ x,     // raw input (for next-slice conversion)
    f16* __restrict__ xpad,          // (512, 66*68, 4)
    const f16* __restrict__ WB,
    const f16* __restrict__ h_in,    // padded (32,66,68,8): h(t-1)
    f16* __restrict__ h_out,         // padded: h(t+3)
    float* __restrict__ c_buf,       // (32,64,64,8) f32: in c(t-1), out c(t+3)
    const float* __restrict__ Wout,  // (32768,4)
    float* __restrict__ partial,     // (256,4)
    int t, int first, int do_head)
{
    __shared__ __attribute__((aligned(16))) char smem[SMEM5];

    const int bid0 = blockIdx.x;
    const int bid  = ((bid0 & 7) << 5) | (bid0 >> 3);   // XCD-contiguous
    const int bi  = bid >> 3;
    const int r0  = (bid & 7) << 3;
    const int tid = threadIdx.x;
    const int w    = __builtin_amdgcn_readfirstlane(tid >> 6);  // 0..15
    const int lane = tid & 63;
    const int p16  = lane & 15;
    const int g4   = lane >> 4;
    const int f0   = g4 << 1;

    // early x-convert source loads: slices t+4..t+7; 2 adjacent px/thread
    const int csl = t + 4 + (tid >> 8);
    const bool cv = (csl < NT);
    const int cpb = (tid & 255) << 1;
    const int cgr = r0 + (cpb >> 6), cgc = cpb & 63;
    float cxa0 = 0.f, cxa1 = 0.f, cxa2 = 0.f;
    float cxb0 = 0.f, cxb1 = 0.f, cxb2 = 0.f;
    if (cv) {
        const float* p = x + ((size_t)(bi * NT + csl) * 4096 + cgr * 64 + cgc) * 3;
        cxa0 = p[0]; cxa1 = p[1]; cxa2 = p[2];
        cxb0 = p[3]; cxb1 = p[4]; cxb2 = p[5];
    }

    // weight fragments
    const half8f* WBv = (const half8f*)WB;
    half8f B00 = WBv[0*64+lane], B01 = WBv[1*64+lane];
    half8f B10 = WBv[2*64+lane], B11 = WBv[3*64+lane];
    half8f B20 = WBv[4*64+lane], B21 = WBv[5*64+lane];
    half8f B30 = WBv[6*64+lane], B31 = WBv[7*64+lane];

    // tap->offset tables (validated r7-r19)
    const int ty0 = (g4 >= 3) ? 1 : 0, tx0 = g4 - 3 * ty0;
    const int ty1 = 1 + ((g4 >= 2) ? 1 : 0), tx1 = (g4 + 4) - 3 * ty1;
    const int ty2 = (g4 == 3) ? 1 : 0, tx2 = (g4 == 2) ? 2 : 0;
    const int ty3 = (g4 == 0) ? 1 : 2, tx3 = (g4 == 1) ? 0 : 2;

    const half8f z8 = {0, 0, 0, 0, 0, 0, 0, 0};

    // ---- prefetch PHASE 1 x operands (slice t+1; 3 tiles/wave, all waves) --
    half8f p1x2[3], p1x3[3];
    #pragma unroll
    for (int k = 0; k < 3; ++k) {
        const int tau = k * 16 + w;
        const int bl = 1 + (tau >> 2), ct = tau & 3;
        const int row = r0 - 3 + bl;       // in-bounds of xpad (slice >= 1)
        const int colA = ct * 16 + p16;
        const char* xpA = (const char*)(xpad +
            ((size_t)((bi * 16 + t + 1) * 66 + row)) * 68 * 4);
        p1x2[k] = LDX(xpA, (ty2 * 68 + colA + tx2) * 8);
        p1x3[k] = LDX(xpA, (ty3 * 68 + colA + tx3) * 8);
    }

    // border cols (0, 65) of all 14 rows, both bands
    if (tid < 56) {
        int buf = tid / 28;
        int r2  = (tid % 28) >> 1;
        int cc  = (tid & 1) ? 65 : 0;
        *(half8f*)(smem + (buf ? BANDB : BANDA) + (r2 * 68 + cc) * 16) = z8;
    }

    // ======== PHASE 0: bl 0..13 (56 tiles), global h/c -> BANDA/cLDS ========
    #pragma unroll
    for (int k = 0; k < 4; ++k) {
        const int tau = k * 16 + w;
        if (tau < 56) {
            const int bl = tau >> 2, ct = tau & 3;
            const int row = r0 - 3 + bl;
            const bool vA = ((unsigned)row < 64u);
            const int colA = ct * 16 + p16;
            float cc0 = 0.f, cc1 = 0.f, hh0 = 0.f, hh1 = 0.f;
            if (vA) {
                floatx2 cold = {0.f, 0.f};
                if (!first)
                    cold = *(const floatx2*)(c_buf +
                               ((size_t)(bi * 4096 + row * 64 + colA)) * 8 + f0);
                const char* hpA = (const char*)(h_in + ((size_t)(bi * 66 + row)) * 68 * 8);
                const char* xpA = (const char*)(xpad +
                    ((size_t)((bi * 16 + t) * 66 + row)) * 68 * 4);
                half8f a0 = first ? z8 : *(const half8f*)(hpA + (ty0 * 68 + colA + tx0) * 16);
                half8f a1 = first ? z8 : *(const half8f*)(hpA + (ty1 * 68 + colA + tx1) * 16);
                half8f a2;
                if (g4 == 0) a2 = first ? z8 : *(const half8f*)(hpA + (2 * 68 + colA + 2) * 16);
                else         a2 = LDX(xpA, (ty2 * 68 + colA + tx2) * 8);
                half8f a3 = LDX(xpA, (ty3 * 68 + colA + tx3) * 8);
                GATE_BODY(a0, a1, a2, a3, cold[0], cold[1], cc0, cc1, hh0, hh1);
            }
            half2f hw = {(f16)hh0, (f16)hh1};
            *(half2f*)(smem + BANDA + (bl * 68 + 1 + colA) * 16 + f0 * 2) = hw;
            if (bl >= 1 && bl <= 12) {
                floatx2 cw = {cc0, cc1};
                *(floatx2*)(smem + CLA(bl - 1, colA)) = cw;
            }
        }
    }
    __syncthreads();

    // ======== PHASE 1: bl 1..12 (48 tiles), BANDA -> BANDB ========
    #pragma unroll
    for (int k = 0; k < 3; ++k) {
        const int tau = k * 16 + w;
        const int bl = 1 + (tau >> 2), ct = tau & 3;
        const int row = r0 - 3 + bl;
        const bool vA = ((unsigned)row < 64u);
        const int colA = ct * 16 + p16;
        float cc0 = 0.f, cc1 = 0.f, hh0 = 0.f, hh1 = 0.f;
        if (vA) {
            floatx2 cold = *(const floatx2*)(smem + CLA(bl - 1, colA));
            half8f a0 = *(const half8f*)(smem + BANDA + ((bl - 1 + ty0) * 68 + colA + tx0) * 16);
            half8f a1 = *(const half8f*)(smem + BANDA + ((bl - 1 + ty1) * 68 + colA + tx1) * 16);
            half8f a2 = (g4 == 0)
                ? *(const half8f*)(smem + BANDA + ((bl + 1) * 68 + colA + 2) * 16)
                : p1x2[k];
            half8f a3 = p1x3[k];
            GATE_BODY(a0, a1, a2, a3, cold[0], cold[1], cc0, cc1, hh0, hh1);
        }
        half2f hw = {(f16)hh0, (f16)hh1};
        *(half2f*)(smem + BANDB + (bl * 68 + 1 + colA) * 16 + f0 * 2) = hw;
        floatx2 cw = {cc0, cc1};
        *(floatx2*)(smem + CLA(bl - 1, colA)) = cw;
    }

    // ---- prefetch PHASE 2 x operands (slice t+2; tau<40) ----
    half8f p2x2[3], p2x3[3];
    #pragma unroll
    for (int k = 0; k < 3; ++k) {
        const int tau = k * 16 + w;
        if (tau < 40) {
            const int bl = 2 + (tau >> 2), ct = tau & 3;
            const int row = r0 - 3 + bl;
            const int colA = ct * 16 + p16;
            const char* xpA = (const char*)(xpad +
                ((size_t)((bi * 16 + t + 2) * 66 + row)) * 68 * 4);
            p2x2[k] = LDX(xpA, (ty2 * 68 + colA + tx2) * 8);
            p2x3[k] = LDX(xpA, (ty3 * 68 + colA + tx3) * 8);
        } else {
            p2x2[k] = z8; p2x3[k] = z8;
        }
    }
    __syncthreads();

    // ======== PHASE 2: bl 2..11 (40 tiles), BANDB -> BANDA ========
    #pragma unroll
    for (int k = 0; k < 3; ++k) {
        const int tau = k * 16 + w;
        if (tau < 40) {
            const int bl = 2 + (tau >> 2), ct = tau & 3;
            const int row = r0 - 3 + bl;
            const bool vA = ((unsigned)row < 64u);
            const int colA = ct * 16 + p16;
            float cc0 = 0.f, cc1 = 0.f, hh0 = 0.f, hh1 = 0.f;
            if (vA) {
                floatx2 cold = *(const floatx2*)(smem + CLA(bl - 1, colA));
                half8f a0 = *(const half8f*)(smem + BANDB + ((bl - 1 + ty0) * 68 + colA + tx0) * 16);
                half8f a1 = *(const half8f*)(smem + BANDB + ((bl - 1 + ty1) * 68 + colA + tx1) * 16);
                half8f a2 = (g4 == 0)
                    ? *(const half8f*)(smem + BANDB + ((bl + 1) * 68 + colA + 2) * 16)
                    : p2x2[k];
                half8f a3 = p2x3[k];
                GATE_BODY(a0, a1, a2, a3, cold[0], cold[1], cc0, cc1, hh0, hh1);
            }
            half2f hw = {(f16)hh0, (f16)hh1};
            *(half2f*)(smem + BANDA + (bl * 68 + 1 + colA) * 16 + f0 * 2) = hw;
            floatx2 cw = {cc0, cc1};
            *(floatx2*)(smem + CLA(bl - 1, colA)) = cw;
        }
    }

    // ---- prefetch PHASE 3 x operands (slice t+3; 2 tiles/wave) ----
    half8f p3x2[2], p3x3[2];
    #pragma unroll
    for (int k = 0; k < 2; ++k) {
        const int tau = k * 16 + w;
        const int bl = 3 + (tau >> 2), ct = tau & 3;
        const int row = r0 - 3 + bl;        // r0..r0+7, always valid
        const int colA = ct * 16 + p16;
        const char* xpA = (const char*)(xpad +
            ((size_t)((bi * 16 + t + 3) * 66 + row)) * 68 * 4);
        p3x2[k] = LDX(xpA, (ty2 * 68 + colA + tx2) * 8);
        p3x3[k] = LDX(xpA, (ty3 * 68 + colA + tx3) * 8);
    }
    __syncthreads();

    // ======== PHASE 3: bl 3..10 (32 tiles), BANDA -> global / head ========
    {
        float ha0 = 0.f, ha1 = 0.f, ha2 = 0.f, ha3 = 0.f;
        #pragma unroll
        for (int k = 0; k < 2; ++k) {
            const int tau = k * 16 + w;
            const int bl = 3 + (tau >> 2), ct = tau & 3;
            const int row = r0 - 3 + bl;
            const int colA = ct * 16 + p16;
            floatx2 cold = *(const floatx2*)(smem + CLA(bl - 1, colA));
            half8f a0 = *(const half8f*)(smem + BANDA + ((bl - 1 + ty0) * 68 + colA + tx0) * 16);
            half8f a1 = *(const half8f*)(smem + BANDA + ((bl - 1 + ty1) * 68 + colA + tx1) * 16);
            half8f a2 = (g4 == 0)
                ? *(const half8f*)(smem + BANDA + ((bl + 1) * 68 + colA + 2) * 16)
                : p3x2[k];
            half8f a3 = p3x3[k];
            float cc0, cc1, hh0, hh1;
            GATE_BODY(a0, a1, a2, a3, cold[0], cold[1], cc0, cc1, hh0, hh1);

            if (!do_head) {
                const size_t gp = (size_t)(bi * 4096 + row * 64 + colA);
                floatx2 cw = {cc0, cc1};
                *(floatx2*)(c_buf + gp * 8 + f0) = cw;
                const size_t hb = ((size_t)(bi * 66 + row + 1) * 68 + 1 + colA) * 8 + f0;
                half2f hw = {(f16)hh0, (f16)hh1};
                *(half2f*)(h_out + hb) = hw;
            } else {
                int pix = row * 64 + colA;
                floatx4 wa  = *(const floatx4*)(Wout + (size_t)(pix * 8 + f0) * 4);
                floatx4 wb2 = *(const floatx4*)(Wout + (size_t)(pix * 8 + f0 + 1) * 4);
                ha0 = fmaf(hh0, wa[0], fmaf(hh1, wb2[0], ha0));
                ha1 = fmaf(hh0, wa[1], fmaf(hh1, wb2[1], ha1));
                ha2 = fmaf(hh0, wa[2], fmaf(hh1, wb2[2], ha2));
                ha3 = fmaf(hh0, wa[3], fmaf(hh1, wb2[3], ha3));
            }
        }

        if (do_head) {
            #pragma unroll
            for (int off = 32; off >= 1; off >>= 1) {
                ha0 += __shfl_down(ha0, off, 64);
                ha1 += __shfl_down(ha1, off, 64);
                ha2 += __shfl_down(ha2, off, 64);
                ha3 += __shfl_down(ha3, off, 64);
            }
            if (lane == 0) {
                floatx4 v = {ha0, ha1, ha2, ha3};
                *(floatx4*)(smem + REDF4 + w * 16) = v;
            }
            __syncthreads();
            if (tid == 0) {
                floatx4 s = {0.f, 0.f, 0.f, 0.f};
                #pragma unroll
                for (int k = 0; k < 16; ++k)
                    s += *(const floatx4*)(smem + REDF4 + k * 16);
                *(floatx4*)(partial + (size_t)bid * 4) = s;
            }
        }
    }

    // x-convert stores (loads issued at kernel start); 2 adjacent pixels
    if (cv) {
        f16* dst = xpad + ((size_t)((bi * 16 + csl) * 66 + cgr + 1) * 68 + cgc + 1) * 4;
        half4f va = {(f16)cxa0, (f16)cxa1, (f16)cxa2, (f16)1.0f};
        half4f vb = {(f16)cxb0, (f16)cxb1, (f16)cxb2, (f16)1.0f};
        *(half4f*)(dst)     = va;
        *(half4f*)(dst + 4) = vb;
    }
}

__global__ __launch_bounds__(64) void head_finish(
    const float* __restrict__ partial,  // (256,4): bid = bi*8+strip
    const float* __restrict__ bout,
    float* __restrict__ out)
{
    int b = threadIdx.x;
    if (b >= NB) return;
    float l0 = bout[0], l1 = bout[1], l2 = bout[2], l3 = bout[3];
    for (int s = 0; s < 8; ++s) {
        floatx4 p = *(const floatx4*)(partial + (size_t)(b * 8 + s) * 4);
        l0 += p[0]; l1 += p[1]; l2 += p[2]; l3 += p[3];
    }
    float m = fmaxf(fmaxf(l0, l1), fmaxf(l2, l3));
    float e0 = expf(l0 - m), e1 = expf(l1 - m);
    float e2 = expf(l2 - m), e3 = expf(l3 - m);
    float inv = 1.0f / (e0 + e1 + e2 + e3);
    out[b * 4 + 0] = e0 * inv;
    out[b * 4 + 1] = e1 * inv;
    out[b * 4 + 2] = e2 * inv;
    out[b * 4 + 3] = e3 * inv;
}

// ========== fallback (ws too small): r8-style LDS per-step path ==========
__global__ __launch_bounds__(256) void prepack_fb(
    const float* __restrict__ Wx, const float* __restrict__ Wh,
    const float* __restrict__ bias, f16* __restrict__ WB)
{
    int i = blockIdx.x * 256 + threadIdx.x;
    if (i < 4096) WB[i] = (f16)wb_entry(i, Wx, Wh, bias);
}

#define FB_XOFF 4352
#define FB_SMEM 6528

#define LDAS(off) ({                                                       \
    half4f lo_ = *(const half4f*)(smem + (off));                           \
    half4f hi_ = *(const half4f*)(smem + (off) + 8);                       \
    __builtin_shufflevector(lo_, hi_, 0, 1, 2, 3, 4, 5, 6, 7); })

__global__ __launch_bounds__(256, 4) void convlstm_step_fb(
    const float* __restrict__ x, const f16* __restrict__ WB,
    const f16* __restrict__ h_in, f16* __restrict__ h_out,
    float* __restrict__ c_buf, int t, int first)
{
    __shared__ __attribute__((aligned(16))) char smem[FB_SMEM];

    const int bid = blockIdx.x;
    const int bi  = bid >> 5;
    const int r0  = (bid & 31) << 1;
    const int tid = threadIdx.x;
    const int w    = tid >> 6;
    const int lane = tid & 63;
    const int p16  = lane & 15;
    const int g4   = lane >> 4;
    const int pr   = w >> 1;
    const int wcol = (w & 1) << 5;

    const float* xt = x + (((size_t)bi * NT + t) * 4096) * 3;

    for (int i = tid; i < 272; i += 256) {
        int lr = i / 68, lc = i - lr * 68;
        int gr = r0 - 1 + lr, gc = lc - 1;
        bool ok = ((unsigned)gr < 64u) && ((unsigned)gc < 64u);
        half4f xv = {0, 0, 0, (f16)1.0f};
        half8f hv = {0, 0, 0, 0, 0, 0, 0, 0};
        if (ok) {
            const float* xp = xt + (gr * 64 + gc) * 3;
            xv[0] = (f16)xp[0]; xv[1] = (f16)xp[1]; xv[2] = (f16)xp[2];
            if (!first)
                hv = *(const half8f*)(h_in + ((size_t)(bi * 4096 + gr * 64 + gc)) * 8);
        }
        *(half8f*)(smem + i * 16) = hv;
        *(half4f*)(smem + FB_XOFF + i * 8) = xv;
    }

    const half8f* WBv = (const half8f*)WB;
    half8f B00 = WBv[0*64+lane], B01 = WBv[1*64+lane];
    half8f B10 = WBv[2*64+lane], B11 = WBv[3*64+lane];
    half8f B20 = WBv[4*64+lane], B21 = WBv[5*64+lane];
    half8f B30 = WBv[6*64+lane], B31 = WBv[7*64+lane];

    const int f0 = g4 << 1;
    const size_t gp0 = (size_t)(bi * 4096 + (r0 + pr) * 64 + wcol + p16);
    const size_t gp1 = gp0 + 16;
    floatx2 cold0 = {0.f, 0.f}, cold1 = {0.f, 0.f};
    if (!first) {
        cold0 = *(const floatx2*)(c_buf + gp0 * 8 + f0);
        cold1 = *(const floatx2*)(c_buf + gp1 * 8 + f0);
    }

    __syncthreads();

    const int ty0 = (g4 >= 3) ? 1 : 0, tx0 = g4 - 3 * ty0;
    const int ty1 = 1 + ((g4 >= 2) ? 1 : 0), tx1 = (g4 + 4) - 3 * ty1;
    const int ty2 = (g4 == 3) ? 1 : 0, tx2 = (g4 == 2) ? 2 : 0;
    const int ty3 = (g4 == 0) ? 1 : 2, tx3 = (g4 == 1) ? 0 : 2;
    const int inc2 = (g4 == 0) ? 256 : 128;
    int o0 = ((pr + ty0) * 68 + wcol + p16 + tx0) * 16;
    int o1 = ((pr + ty1) * 68 + wcol + p16 + tx1) * 16;
    int o2 = (g4 == 0) ? ((pr + 2) * 68 + wcol + p16 + 2) * 16
                       : FB_XOFF + ((pr + ty2) * 68 + wcol + p16 + tx2) * 8;
    int o3 = FB_XOFF + ((pr + ty3) * 68 + wcol + p16 + tx3) * 8;

    #pragma unroll
    for (int tt = 0; tt < 2; ++tt) {
        half8f a0 = LDAS(o0), a1 = LDAS(o1), a2 = LDAS(o2), a3 = LDAS(o3);
        floatx2 cold = tt ? cold1 : cold0;
        float cc0, cc1, hh0, hh1;
        GATE_BODY(a0, a1, a2, a3, cold[0], cold[1], cc0, cc1, hh0, hh1);
        const size_t gp = tt ? gp1 : gp0;
        floatx2 cw = {cc0, cc1};
        *(floatx2*)(c_buf + gp * 8 + f0) = cw;
        half2f hw = {(f16)hh0, (f16)hh1};
        *(half2f*)(h_out + gp * 8 + f0) = hw;
        o0 += 256; o1 += 256; o2 += inc2; o3 += 128;
    }
}

__global__ __launch_bounds__(256) void head_partial_fb(
    const f16* __restrict__ h, const float* __restrict__ Wout,
    float* __restrict__ partial)
{
    const int b = blockIdx.x >> 4;
    const int chunk = blockIdx.x & 15;
    const int tid = threadIdx.x;
    const f16* hb = h + (size_t)b * 32768 + chunk * 2048;
    const float* wb = Wout + (size_t)(chunk * 2048) * 4;

    float acc[4] = {0.f, 0.f, 0.f, 0.f};
    #pragma unroll
    for (int it = 0; it < 8; ++it) {
        int i = it * 256 + tid;
        float hv = (float)hb[i];
        float4 wv = *(const float4*)(wb + (size_t)i * 4);
        acc[0] = fmaf(hv, wv.x, acc[0]);
        acc[1] = fmaf(hv, wv.y, acc[1]);
        acc[2] = fmaf(hv, wv.z, acc[2]);
        acc[3] = fmaf(hv, wv.w, acc[3]);
    }
    #pragma unroll
    for (int j = 0; j < 4; ++j)
        #pragma unroll
        for (int off = 32; off >= 1; off >>= 1)
            acc[j] += __shfl_down(acc[j], off, 64);

    __shared__ float red2[4][4];
    int lane = tid & 63, wv2 = tid >> 6;
    if (lane == 0) {
        #pragma unroll
        for (int j = 0; j < 4; ++j) red2[wv2][j] = acc[j];
    }
    __syncthreads();
    if (tid == 0) {
        #pragma unroll
        for (int j = 0; j < 4; ++j)
            partial[(size_t)blockIdx.x * 4 + j] =
                red2[0][j] + red2[1][j] + red2[2][j] + red2[3][j];
    }
}

__global__ __launch_bounds__(64) void head_finish_fb(
    const float* __restrict__ partial, const float* __restrict__ bout,
    float* __restrict__ out)
{
    int b = threadIdx.x;
    if (b >= NB) return;
    float logit[4] = {bout[0], bout[1], bout[2], bout[3]};
    #pragma unroll
    for (int k = 0; k < 16; ++k) {
        const float* p = partial + (size_t)(b * 16 + k) * 4;
        logit[0] += p[0]; logit[1] += p[1]; logit[2] += p[2]; logit[3] += p[3];
    }
    float m = fmaxf(fmaxf(logit[0], logit[1]), fmaxf(logit[2], logit[3]));
    float e[4], s = 0.f;
    #pragma unroll
    for (int j = 0; j < 4; ++j) { e[j] = expf(logit[j] - m); s += e[j]; }
    float inv = 1.0f / s;
    #pragma unroll
    for (int j = 0; j < 4; ++j) out[b * 4 + j] = e[j] * inv;
}

extern "C" void kernel_launch(void* const* d_in, const int* in_sizes, int n_in,
                              void* d_out, int out_size, void* d_ws, size_t ws_size,
                              hipStream_t stream) {
    const float* x    = (const float*)d_in[0];
    const float* Wx   = (const float*)d_in[1];
    const float* Wh   = (const float*)d_in[2];
    const float* b    = (const float*)d_in[3];
    const float* Wout = (const float*)d_in[4];
    const float* bout = (const float*)d_in[5];
    float* out = (float*)d_out;
    char* ws = (char*)d_ws;

    if (ws_size >= WS_NEED) {
        f16*   xpad  = (f16*)(ws + XPAD_OFF);
        f16*   h0    = (f16*)(ws + HPAD0_OFF);
        f16*   h1    = (f16*)(ws + HPAD1_OFF);
        float* cb    = (float*)(ws + CBUF_OFF);
        f16*   WBq   = (f16*)(ws + WBQ_OFF);
        float* part  = (float*)(ws + PART_OFF);

        init_all<<<2946, 256, 0, stream>>>(x, Wx, Wh, b, xpad, h0, h1, WBq);

        // fused kernel k covers t = 4k..4k+3; converts x slices 4k+4..4k+7.
        for (int k = 0; k < 4; ++k) {
            const f16* hin  = (k & 1) ? h0 : h1;   // k=0: h1 (unused, first)
            f16*       hout = (k & 1) ? h1 : h0;
            convlstm_fused4w<<<256, 1024, 0, stream>>>(
                x, xpad, WBq, hin, hout, cb, Wout, part,
                4 * k, (k == 0) ? 1 : 0, (k == 3) ? 1 : 0);
        }
        head_finish<<<1, 64, 0, stream>>>(part, bout, out);
    } else {
        f16*   hA      = (f16*)ws;                    // 2 MB
        f16*   hB      = (f16*)(ws + (1u << 21));     // 2 MB
        float* cb      = (float*)(ws + (1u << 22));   // 4 MB
        f16*   WBq     = (f16*)(ws + (1u << 23));     // 8 KB
        float* partial = (float*)(ws + (1u << 23) + 8192);

        prepack_fb<<<16, 256, 0, stream>>>(Wx, Wh, b, WBq);
        for (int t = 0; t < NT; ++t) {
            const f16* hin = (t & 1) ? hA : hB;
            f16*       hout = (t & 1) ? hB : hA;
            convlstm_step_fb<<<1024, 256, 0, stream>>>(x, WBq, hin, hout, cb,
                                                       t, (t == 0) ? 1 : 0);
        }
        head_partial_fb<<<512, 256, 0, stream>>>(hB, Wout, partial);
        head_finish_fb<<<1, 64, 0, stream>>>(partial, bout, out);
    }
}